// Round 9
// baseline (392.393 us; speedup 1.0000x reference)
//
#include <hip/hip_runtime.h>
#include <hip/hip_bf16.h>
#include <cstdint>
#include <cstddef>

#define Bb  256
#define Ss  196
#define Hh  1024
#define SP1 197
#define Mm  50176   // Bb*Ss

typedef float  f32x4 __attribute__((ext_vector_type(4)));
typedef short  s16x8 __attribute__((ext_vector_type(8)));
typedef unsigned short u16;
typedef unsigned short u16x4 __attribute__((ext_vector_type(4)));
typedef unsigned short u16x8 __attribute__((ext_vector_type(8)));

__device__ __forceinline__ u16 f2b(float f) {
  __hip_bfloat16 b = __float2bfloat16(f);   // RNE
  u16 r; __builtin_memcpy(&r, &b, 2); return r;
}
__device__ __forceinline__ float b2f(u16 u) {
  return __uint_as_float(((unsigned)u) << 16);
}
// fast tanh: rel err ~1e-6 (vs bf16 4e-3 budget)
__device__ __forceinline__ float ftanh(float x) {
  float ax = fabsf(x);
  float t = __expf(-2.f * ax);
  float r = (1.f - t) * __builtin_amdgcn_rcpf(1.f + t);
  return copysignf(r, x);
}
__device__ __forceinline__ void gload16(const u16* g, u16* l) {
  __builtin_amdgcn_global_load_lds(
      (const __attribute__((address_space(1))) unsigned int*)(const void*)g,
      (__attribute__((address_space(3))) unsigned int*)(void*)l, 16, 0, 0);
}

// ---------------- cvt: V f32 -> Vb bf16 LINEAR, fully coalesced (G2) ----------
// lane i handles 4-float group g: 16B/lane contiguous load, 8B/lane store.
__device__ __forceinline__ void cvt_core(int bid, const float* __restrict__ V,
                                         u16* __restrict__ Vb) {
  const size_t total = (size_t)Mm * (Hh / 4);   // 12,845,056 groups
  for (size_t g = (size_t)bid * 256 + threadIdx.x; g < total;
       g += (size_t)2048 * 256) {
    f32x4 a = *(const f32x4*)(V + g * 4);
    u16x4 w;
    w[0] = f2b(a.x); w[1] = f2b(a.y); w[2] = f2b(a.z); w[3] = f2b(a.w);
    *(u16x4*)(Vb + g * 4) = w;
  }
}

// W_v [K][N] f32 -> WvT [N][K] bf16 with baked XOR swizzle on k
__device__ __forceinline__ void transpose_core(int bid, float* sm,
                                               const float* __restrict__ Wv,
                                               u16* __restrict__ WvT) {
  float (*t)[65] = (float(*)[65])sm;
  int k0 = (bid & 15) * 64;
  int n0 = (bid >> 4) * 64;
  int tid = threadIdx.x;
#pragma unroll
  for (int i = 0; i < 16; ++i) {
    int idx = i * 256 + tid;
    int r = idx >> 6, c = idx & 63;
    t[r][c] = Wv[(size_t)(k0 + r) * Hh + n0 + c];
  }
  __syncthreads();
#pragma unroll
  for (int i = 0; i < 16; ++i) {
    int idx = i * 256 + tid;
    int r = idx >> 6, c = idx & 63;          // r: n-dim, c: k-dim
    WvT[(size_t)(n0 + r) * Hh + ((k0 + c) ^ ((r & 7) << 3))] = f2b(t[c][r]);
  }
}

// small GEMM: Y[32 x 64] = act(X@W + b); 4 waves split K (256 each).
__device__ __forceinline__ void small_gemm_core(int bid, int nct, float* sm,
    const float* __restrict__ X, int ldx,
    const float* __restrict__ W, int ldw,
    const float* __restrict__ bias,
    float* __restrict__ Y, int ldy, int act) {
  // sm used as xs[4][32][64] (32 KB)
  int tid = threadIdx.x, lane = tid & 63, w = tid >> 6;
  int ct = bid % nct, bt = bid / nct;
  int col = ct * 64 + lane;
  float acc[32];
#pragma unroll
  for (int b = 0; b < 32; ++b) acc[b] = 0.f;
  int xr = lane >> 1, xc = (lane & 1) * 32;
  for (int kc = 0; kc < 4; ++kc) {
    int kb = w * 256 + kc * 64;
#pragma unroll
    for (int q = 0; q < 8; ++q)
      *(f32x4*)&sm[(w * 32 + xr) * 64 + xc + q * 4] =
          *(const f32x4*)&X[(size_t)(bt * 32 + xr) * ldx + kb + xc + q * 4];
    // wave-private region; in-wave ds ordering suffices (benched R3-R8)
    for (int kl = 0; kl < 64; kl += 4) {
      float w0 = W[(size_t)(kb + kl + 0) * ldw + col];
      float w1 = W[(size_t)(kb + kl + 1) * ldw + col];
      float w2 = W[(size_t)(kb + kl + 2) * ldw + col];
      float w3 = W[(size_t)(kb + kl + 3) * ldw + col];
#pragma unroll
      for (int b = 0; b < 32; ++b) {
        f32x4 x = *(const f32x4*)&sm[(w * 32 + b) * 64 + kl];
        acc[b] += x.x * w0 + x.y * w1 + x.z * w2 + x.w * w3;
      }
    }
  }
#pragma unroll
  for (int b = 0; b < 32; ++b) sm[(w * 32 + b) * 64 + lane] = acc[b];
  __syncthreads();
#pragma unroll
  for (int q = 0; q < 8; ++q) {
    int b = w * 8 + q;
    float s = sm[(0 * 32 + b) * 64 + lane] + sm[(1 * 32 + b) * 64 + lane]
            + sm[(2 * 32 + b) * 64 + lane] + sm[(3 * 32 + b) * 64 + lane]
            + bias[col];
    if (act) s = ftanh(s);
    Y[(size_t)(bt * 32 + b) * ldy + col] = s;
  }
}

// k_pre1: transposeWv (256 blocks) | fc (256 blocks: 32ct x 8bt)
__global__ __launch_bounds__(256) void k_pre1(const float* __restrict__ Wv,
                                              u16* __restrict__ WvT,
                                              const float* __restrict__ h,
                                              const float* __restrict__ Wfc,
                                              const float* __restrict__ bfc,
                                              float* __restrict__ hs) {
  __shared__ __align__(16) float sm[4 * 32 * 64];
  int bid = blockIdx.x;
  if (bid < 256) transpose_core(bid, sm, Wv, WvT);
  else small_gemm_core(bid - 256, 32, sm, h, Hh, Wfc, 2048, bfc, hs, 2048, 1);
}

// k_pre2: cvt (2048 blocks, coalesced grid-stride) | dual hh/sv (256 blocks)
__global__ __launch_bounds__(256) void k_pre2(const float* __restrict__ v,
                                              u16* __restrict__ Vb, int pre,
                                              const float* __restrict__ hs,
                                              const float* __restrict__ Wh,
                                              const float* __restrict__ bh,
                                              const float* __restrict__ Ws_,
                                              const float* __restrict__ bs_,
                                              float* __restrict__ hhp,
                                              float* __restrict__ svp) {
  __shared__ __align__(16) float sm[4 * 32 * 64];
  int bid = blockIdx.x;
  if (bid < 2048) {
    if (pre) cvt_core(bid, v, Vb);
  } else {
    int b2 = bid - 2048;               // 0..255: 128 hh + 128 sv
    int sel = b2 >= 128;
    small_gemm_core(b2 - (sel << 7), 16, sm,
                    sel ? hs + 1024 : hs, 2048,
                    sel ? Ws_ : Wh, Hh,
                    sel ? bs_ : bh,
                    sel ? svp : hhp, Hh, 0);
  }
}

// ---------------- K3: fused big GEMM + tanh + Wz-dot epilogue ------------------
// R6-proven structure: 128x128 tile, BK=64, 4 waves 2x2, single buffer,
// stage -> barrier -> compute, 4 blocks/CU. A source address per-lane
// pre-swizzled (Vb linear, HK m173 pattern); B from baked-swizzled WvT.
#define BK 64
template<int PRE>
__global__ __launch_bounds__(256, PRE ? 4 : 3)
void k_big(const float* __restrict__ V, const u16* __restrict__ Vb,
           const u16* __restrict__ WvT, const float* __restrict__ bv,
           const float* __restrict__ hh, const float* __restrict__ Wz,
           float* __restrict__ zpart) {
  constexpr int LDA_ = PRE ? 64 : 72;
  __shared__ __align__(16) u16 As[128 * LDA_];
  __shared__ __align__(16) u16 Bs[128 * 64];
  __shared__ float wz_s[128], bv_s[128], hh_s[2][128];
  __shared__ float zred[4][64];

  int bid = blockIdx.x;
  int lin = (bid & 7) * 392 + (bid >> 3);   // 3136 = 8*392, bijective XCD swizzle
  int mt = lin >> 3, nt = lin & 7;          // 8 nt of one mt share an XCD
  int row0 = mt * 128, n0 = nt * 128;

  int tid = threadIdx.x;
  int lane = tid & 63, wid = tid >> 6;
  int wm = wid >> 1, wn = wid & 1;

  int b0 = row0 / Ss;
  int rsplit = (b0 + 1) * Ss - row0;        // rows >= rsplit -> batch b0+1
  int b1 = (rsplit < 128) ? b0 + 1 : b0;
  if (tid < 128) {
    wz_s[tid] = Wz[n0 + tid];
    bv_s[tid] = bv[n0 + tid];
    hh_s[0][tid] = hh[(size_t)b0 * Hh + n0 + tid];
    hh_s[1][tid] = hh[(size_t)b1 * Hh + n0 + tid];
  }

  f32x4 acc[4][4];
  f32x4 zz = {0.f, 0.f, 0.f, 0.f};
#pragma unroll
  for (int m = 0; m < 4; ++m)
#pragma unroll
    for (int n = 0; n < 4; ++n) acc[m][n] = zz;

  int srow = lane >> 3, scol = (lane & 7) * 8;   // staging lane offsets
  int ascol = scol ^ (srow << 3);                // A source col (inverse swizzle)
  int bxor = (lane & 7) << 3;                    // read-side XOR (row&7==lane&7)

  // PRE=0 reg staging state
  int arow = tid >> 3, acol8 = (tid & 7) * 8;
  const float* Ap = V + (size_t)(row0 + arow) * Hh + acol8;
  f32x4 av[8];
  if constexpr (!PRE) {
#pragma unroll
    for (int j = 0; j < 4; ++j) {
      av[2 * j]     = *(const f32x4*)(Ap + (size_t)j * 32 * Hh);
      av[2 * j + 1] = *(const f32x4*)(Ap + (size_t)j * 32 * Hh + 4);
    }
  }

  for (int kt = 0; kt < 16; ++kt) {
    int k0 = kt * BK;
    __syncthreads();                   // prev compute done; LDS writable
    if constexpr (PRE) {
#pragma unroll
      for (int i = 0; i < 4; ++i) {    // B staging
        int r = wid * 32 + i * 8;
        gload16(WvT + (size_t)(n0 + r + srow) * Hh + k0 + scol, &Bs[r * 64]);
      }
#pragma unroll
      for (int i = 0; i < 4; ++i) {    // A staging, pre-swizzled source
        int r = wid * 32 + i * 8;
        gload16(Vb + (size_t)(row0 + r + srow) * Hh + k0 + ascol, &As[r * 64]);
      }
    } else {
#pragma unroll
      for (int i = 0; i < 4; ++i) {
        int r = wid * 32 + i * 8;
        gload16(WvT + (size_t)(n0 + r + srow) * Hh + k0 + scol, &Bs[r * 64]);
      }
#pragma unroll
      for (int j = 0; j < 4; ++j) {
        u16x8 w;
        w[0] = f2b(av[2 * j].x);     w[1] = f2b(av[2 * j].y);
        w[2] = f2b(av[2 * j].z);     w[3] = f2b(av[2 * j].w);
        w[4] = f2b(av[2 * j + 1].x); w[5] = f2b(av[2 * j + 1].y);
        w[6] = f2b(av[2 * j + 1].z); w[7] = f2b(av[2 * j + 1].w);
        *(u16x8*)&As[(j * 32 + arow) * LDA_ + acol8] = w;
      }
      if (kt < 15) {
#pragma unroll
        for (int j = 0; j < 4; ++j) {
          av[2 * j]     = *(const f32x4*)(Ap + (size_t)j * 32 * Hh + k0 + BK);
          av[2 * j + 1] = *(const f32x4*)(Ap + (size_t)j * 32 * Hh + k0 + BK + 4);
        }
      }
    }
    __syncthreads();                   // drains staging
#pragma unroll
    for (int ks = 0; ks < 2; ++ks) {
      int kk = ks * 32 + (lane >> 4) * 8;
      s16x8 afr[4], bfr[4];
#pragma unroll
      for (int m = 0; m < 4; ++m) {
        int r = wm * 64 + m * 16 + (lane & 15);
        afr[m] = *(const s16x8*)&As[r * LDA_ + (PRE ? (kk ^ bxor) : kk)];
      }
#pragma unroll
      for (int n = 0; n < 4; ++n) {
        int r = wn * 64 + n * 16 + (lane & 15);
        bfr[n] = *(const s16x8*)&Bs[r * 64 + (kk ^ bxor)];
      }
#pragma unroll
      for (int m = 0; m < 4; ++m)
#pragma unroll
        for (int n = 0; n < 4; ++n)
          acc[m][n] = __builtin_amdgcn_mfma_f32_16x16x32_bf16(afr[m], bfr[n], acc[m][n], 0, 0, 0);
    }
  }

  // epilogue: z-partial over this block's 128 cols
  int cl = lane & 15, rg = lane >> 4;
  float pz[4][4];
#pragma unroll
  for (int m = 0; m < 4; ++m)
#pragma unroll
    for (int j = 0; j < 4; ++j) pz[m][j] = 0.f;
#pragma unroll
  for (int n = 0; n < 4; ++n) {
    int col = wn * 64 + n * 16 + cl;
    float wzv = wz_s[col], bvv = bv_s[col];
    float h0 = hh_s[0][col], h1 = hh_s[1][col];
#pragma unroll
    for (int m = 0; m < 4; ++m)
#pragma unroll
      for (int j = 0; j < 4; ++j) {
        int r = wm * 64 + m * 16 + rg * 4 + j;
        float hv = (r >= rsplit) ? h1 : h0;
        pz[m][j] += wzv * ftanh(acc[m][n][j] + bvv + hv);
      }
  }
#pragma unroll
  for (int m = 0; m < 4; ++m)
#pragma unroll
    for (int j = 0; j < 4; ++j) {
      float vv = pz[m][j];
      vv += __shfl_xor(vv, 1); vv += __shfl_xor(vv, 2);
      vv += __shfl_xor(vv, 4); vv += __shfl_xor(vv, 8);
      pz[m][j] = vv;
    }
  if (cl == 0) {
#pragma unroll
    for (int m = 0; m < 4; ++m)
#pragma unroll
      for (int j = 0; j < 4; ++j)
        zred[wid][m * 16 + rg * 4 + j] = pz[m][j];
  }
  __syncthreads();
  if (tid < 128) {
    int hhalf = tid >> 6, lr = tid & 63;
    zpart[(size_t)nt * Mm + row0 + tid] =
        zred[hhalf * 2][lr] + zred[hhalf * 2 + 1][lr];
  }
}

// ---------------- K4: softmax over 197 per batch (zS folded in) ----------------
__global__ __launch_bounds__(256) void k_softmax(const float* __restrict__ zpart,
                                                 const float* __restrict__ sv,
                                                 const float* __restrict__ hhp,
                                                 const float* __restrict__ Wz,
                                                 const float* __restrict__ bz,
                                                 float* __restrict__ outA) {
  int b = blockIdx.x, tid = threadIdx.x;
  int wid = tid >> 6, lane = tid & 63;
  __shared__ float redm[4], reds[4];
  __shared__ float zSsh;
  {
    int j0 = tid * 4;
    f32x4 s4 = *(const f32x4*)&sv[(size_t)b * Hh + j0];
    f32x4 h4 = *(const f32x4*)&hhp[(size_t)b * Hh + j0];
    f32x4 w4 = *(const f32x4*)&Wz[j0];
    float p = w4.x * ftanh(s4.x + h4.x) + w4.y * ftanh(s4.y + h4.y)
            + w4.z * ftanh(s4.z + h4.z) + w4.w * ftanh(s4.w + h4.w);
#pragma unroll
    for (int d = 1; d < 64; d <<= 1) p += __shfl_xor(p, d);
    if (lane == 0) redm[wid] = p;
    __syncthreads();
    if (tid == 0) zSsh = redm[0] + redm[1] + redm[2] + redm[3] + bz[0];
    __syncthreads();
  }
  float z = -1e30f;
  if (tid < Ss) {
    float s = 0.f;
#pragma unroll
    for (int nt = 0; nt < 8; ++nt) s += zpart[(size_t)nt * Mm + (size_t)b * Ss + tid];
    z = s + bz[0];
  } else if (tid == Ss) {
    z = zSsh;
  }
  float m = z;
#pragma unroll
  for (int d = 1; d < 64; d <<= 1) m = fmaxf(m, __shfl_xor(m, d));
  if (lane == 0) redm[wid] = m;
  __syncthreads();
  m = fmaxf(fmaxf(redm[0], redm[1]), fmaxf(redm[2], redm[3]));
  float e = (tid <= Ss) ? expf(z - m) : 0.f;
  float s = e;
#pragma unroll
  for (int d = 1; d < 64; d <<= 1) s += __shfl_xor(s, d);
  if (lane == 0) reds[wid] = s;
  __syncthreads();
  s = reds[0] + reds[1] + reds[2] + reds[3];
  if (tid <= Ss) outA[(size_t)b * SP1 + tid] = e / s;
}

// ---------------- K5: c[b,:] = sum_t a[b,t]*v[b,t,:] + a[b,S]*s[b,:] -----------
// PRE=1: row-streamed u16x4 loads from linear Vb (8B/lane coalesced).
template<int PRE>
__global__ __launch_bounds__(256) void k_ctx(const float* __restrict__ V,
                                             const u16* __restrict__ Vb,
                                             const float* __restrict__ hs,
                                             const float* __restrict__ A,
                                             float* __restrict__ outC) {
  __shared__ float a_s[SP1];
  if constexpr (PRE) {
    int b = blockIdx.x;                 // 256 blocks, thread owns 4 cols
    int c4 = threadIdx.x * 4;
    if (threadIdx.x < SP1) a_s[threadIdx.x] = A[(size_t)b * SP1 + threadIdx.x];
    __syncthreads();
    f32x4 hv = *(const f32x4*)&hs[(size_t)b * 2048 + 1024 + c4];
    float aS = a_s[Ss];
    f32x4 acc = {aS * hv.x, aS * hv.y, aS * hv.z, aS * hv.w};
    const u16* vb = Vb + (size_t)b * Ss * Hh + c4;
#pragma unroll 4
    for (int t = 0; t < Ss; ++t) {
      u16x4 w = *(const u16x4*)(vb + (size_t)t * Hh);
      float at = a_s[t];
      acc.x += at * b2f(w[0]); acc.y += at * b2f(w[1]);
      acc.z += at * b2f(w[2]); acc.w += at * b2f(w[3]);
    }
    *(f32x4*)&outC[(size_t)b * Hh + c4] = acc;
  } else {
    int b = blockIdx.x >> 2;
    int col = (blockIdx.x & 3) * 256 + threadIdx.x;
    if (threadIdx.x < SP1) a_s[threadIdx.x] = A[(size_t)b * SP1 + threadIdx.x];
    __syncthreads();
    float acc = a_s[Ss] * hs[(size_t)b * 2048 + 1024 + col];
    const float* vb = V + (size_t)b * Ss * Hh + col;
#pragma unroll 4
    for (int t = 0; t < Ss; ++t) acc += a_s[t] * vb[(size_t)t * Hh];
    outC[(size_t)b * Hh + col] = acc;
  }
}

// -------------------------------------------------------------------------------
extern "C" void kernel_launch(void* const* d_in, const int* in_sizes, int n_in,
                              void* d_out, int out_size, void* d_ws, size_t ws_size,
                              hipStream_t stream) {
  const float* v   = (const float*)d_in[0];
  const float* h   = (const float*)d_in[1];
  const float* Wfc = (const float*)d_in[2];
  const float* bfc = (const float*)d_in[3];
  const float* Wv  = (const float*)d_in[4];
  const float* bv  = (const float*)d_in[5];
  const float* Wh  = (const float*)d_in[6];
  const float* bh  = (const float*)d_in[7];
  const float* Ws  = (const float*)d_in[8];
  const float* bs  = (const float*)d_in[9];
  const float* Wz  = (const float*)d_in[10];
  const float* bz  = (const float*)d_in[11];
  float* out  = (float*)d_out;
  float* outA = out;                         // [256][197]
  float* outC = out + (size_t)Bb * SP1;      // [256][1024]

  float* ws  = (float*)d_ws;
  float* hs  = ws;                  // 524288 f
  float* hh  = hs + 524288;         // 262144 f
  float* sv  = hh + 262144;         // 262144 f
  float* zp  = sv + 262144;         // 8*50176 f
  u16*  WvT  = (u16*)(zp + 401408); // 1M u16 (swizzled)
  u16*  Vb   = (u16*)((char*)(void*)WvT + 2097152);  // 50176*1024 u16 (LINEAR)

  // bytes needed through Vb: 7897088 + 102760448
  bool pre = ws_size >= 110657536ull;

  k_pre1<<<512, 256, 0, stream>>>(Wv, WvT, h, Wfc, bfc, hs);
  k_pre2<<<2304, 256, 0, stream>>>(v, Vb, (int)pre, hs, Wh, bh, Ws, bs, hh, sv);
  if (pre) k_big<1><<<3136, 256, 0, stream>>>(v, Vb, WvT, bv, hh, Wz, zp);
  else     k_big<0><<<3136, 256, 0, stream>>>(v, Vb, WvT, bv, hh, Wz, zp);
  k_softmax<<<256, 256, 0, stream>>>(zp, sv, hh, Wz, bz, outA);
  if (pre) k_ctx<1><<<256, 256, 0, stream>>>(v, Vb, hs, outA, outC);
  else     k_ctx<0><<<1024, 256, 0, stream>>>(v, Vb, hs, outA, outC);
}

// Round 10
// 271.286 us; speedup vs baseline: 1.4464x; 1.4464x over previous
//
#include <hip/hip_runtime.h>
#include <hip/hip_bf16.h>
#include <cstdint>
#include <cstddef>

#define Bb  256
#define Ss  196
#define Hh  1024
#define SP1 197
#define Mm  50176   // Bb*Ss

typedef float  f32x4 __attribute__((ext_vector_type(4)));
typedef short  s16x8 __attribute__((ext_vector_type(8)));
typedef unsigned short u16;
typedef unsigned short u16x4 __attribute__((ext_vector_type(4)));
typedef unsigned short u16x8 __attribute__((ext_vector_type(8)));

__device__ __forceinline__ u16 f2b(float f) {
  __hip_bfloat16 b = __float2bfloat16(f);   // RNE
  u16 r; __builtin_memcpy(&r, &b, 2); return r;
}
__device__ __forceinline__ float b2f(u16 u) {
  return __uint_as_float(((unsigned)u) << 16);
}
// fast tanh: rel err ~1e-6 (vs bf16 4e-3 budget)
__device__ __forceinline__ float ftanh(float x) {
  float ax = fabsf(x);
  float t = __expf(-2.f * ax);
  float r = (1.f - t) * __builtin_amdgcn_rcpf(1.f + t);
  return copysignf(r, x);
}
__device__ __forceinline__ void gload16(const u16* g, u16* l) {
  __builtin_amdgcn_global_load_lds(
      (const __attribute__((address_space(1))) unsigned int*)(const void*)g,
      (__attribute__((address_space(3))) unsigned int*)(void*)l, 16, 0, 0);
}

// ---------------- cvt: V f32 -> Vb bf16 LINEAR, coalesced (G2) ----------------
__device__ __forceinline__ void cvt_core(int bid, const float* __restrict__ V,
                                         u16* __restrict__ Vb) {
  const size_t total = (size_t)Mm * (Hh / 4);   // 12,845,056 groups of 4
  for (size_t g = (size_t)bid * 256 + threadIdx.x; g < total;
       g += (size_t)2048 * 256) {
    f32x4 a = *(const f32x4*)(V + g * 4);
    u16x4 w;
    w[0] = f2b(a.x); w[1] = f2b(a.y); w[2] = f2b(a.z); w[3] = f2b(a.w);
    *(u16x4*)(Vb + g * 4) = w;
  }
}

// W_v [K][N] f32 -> WvT [N][K] bf16 with baked XOR swizzle on k
__device__ __forceinline__ void transpose_core(int bid, float* sm,
                                               const float* __restrict__ Wv,
                                               u16* __restrict__ WvT) {
  float (*t)[65] = (float(*)[65])sm;
  int k0 = (bid & 15) * 64;
  int n0 = (bid >> 4) * 64;
  int tid = threadIdx.x;
#pragma unroll
  for (int i = 0; i < 16; ++i) {
    int idx = i * 256 + tid;
    int r = idx >> 6, c = idx & 63;
    t[r][c] = Wv[(size_t)(k0 + r) * Hh + n0 + c];
  }
  __syncthreads();
#pragma unroll
  for (int i = 0; i < 16; ++i) {
    int idx = i * 256 + tid;
    int r = idx >> 6, c = idx & 63;          // r: n-dim, c: k-dim
    WvT[(size_t)(n0 + r) * Hh + ((k0 + c) ^ ((r & 7) << 3))] = f2b(t[c][r]);
  }
}

// small GEMM (R3/R4-proven ROWS=16): Y[16 x 64] = act(X@W + b); 4 waves split K
__device__ __forceinline__ void small_gemm_core(int bid, int nct, float* sm,
    const float* __restrict__ X, int ldx,
    const float* __restrict__ W, int ldw,
    const float* __restrict__ bias,
    float* __restrict__ Y, int ldy, int act) {
  // sm used as xs[4][16][64] (16 KB)
  int tid = threadIdx.x, lane = tid & 63, w = tid >> 6;
  int ct = bid % nct, bt = bid / nct;
  int col = ct * 64 + lane;
  float acc[16];
#pragma unroll
  for (int b = 0; b < 16; ++b) acc[b] = 0.f;
  int xr = lane >> 2, xc = (lane & 3) * 16;
  for (int kc = 0; kc < 4; ++kc) {
    int kb = w * 256 + kc * 64;
#pragma unroll
    for (int q = 0; q < 4; ++q)
      *(f32x4*)&sm[(w * 16 + xr) * 64 + xc + q * 4] =
          *(const f32x4*)&X[(size_t)(bt * 16 + xr) * ldx + kb + xc + q * 4];
    // wave-private region; in-wave ds ordering suffices (benched R3-R9)
    for (int kl = 0; kl < 64; kl += 4) {
      float w0 = W[(size_t)(kb + kl + 0) * ldw + col];
      float w1 = W[(size_t)(kb + kl + 1) * ldw + col];
      float w2 = W[(size_t)(kb + kl + 2) * ldw + col];
      float w3 = W[(size_t)(kb + kl + 3) * ldw + col];
#pragma unroll
      for (int b = 0; b < 16; ++b) {
        f32x4 x = *(const f32x4*)&sm[(w * 16 + b) * 64 + kl];
        acc[b] += x.x * w0 + x.y * w1 + x.z * w2 + x.w * w3;
      }
    }
  }
#pragma unroll
  for (int b = 0; b < 16; ++b) sm[(w * 16 + b) * 64 + lane] = acc[b];
  __syncthreads();
#pragma unroll
  for (int q = 0; q < 4; ++q) {
    int b = w * 4 + q;
    float s = sm[(0 * 16 + b) * 64 + lane] + sm[(1 * 16 + b) * 64 + lane]
            + sm[(2 * 16 + b) * 64 + lane] + sm[(3 * 16 + b) * 64 + lane]
            + bias[col];
    if (act) s = ftanh(s);
    Y[(size_t)(bt * 16 + b) * ldy + col] = s;
  }
}

// k_pre1: transpose(256) | fc(512: 32ct x 16bt) | cvt(2048 grid-stride, last)
__global__ __launch_bounds__(256) void k_pre1(const float* __restrict__ v,
                                              u16* __restrict__ Vb, int pre,
                                              const float* __restrict__ Wv,
                                              u16* __restrict__ WvT,
                                              const float* __restrict__ h,
                                              const float* __restrict__ Wfc,
                                              const float* __restrict__ bfc,
                                              float* __restrict__ hs) {
  __shared__ __align__(16) float sm[64 * 65];
  int bid = blockIdx.x;
  if (bid < 256) transpose_core(bid, sm, Wv, WvT);
  else if (bid < 768)
    small_gemm_core(bid - 256, 32, sm, h, Hh, Wfc, 2048, bfc, hs, 2048, 1);
  else if (pre) cvt_core(bid - 768, v, Vb);
}

// k_dual: hh (256 blocks) | sv (256 blocks), ROWS=16, nct=16
__global__ __launch_bounds__(256) void k_dual(const float* __restrict__ hs,
                                              const float* __restrict__ Wh,
                                              const float* __restrict__ bh,
                                              const float* __restrict__ Ws_,
                                              const float* __restrict__ bs_,
                                              float* __restrict__ hhp,
                                              float* __restrict__ svp) {
  __shared__ __align__(16) float sm[4 * 16 * 64];
  int bid = blockIdx.x;
  int sel = bid >= 256;
  small_gemm_core(bid - (sel << 8), 16, sm,
                  sel ? hs + 1024 : hs, 2048,
                  sel ? Ws_ : Wh, Hh,
                  sel ? bs_ : bh,
                  sel ? svp : hhp, Hh, 0);
}

// ---------------- K3: fused big GEMM + tanh + Wz-dot epilogue ------------------
// R6-proven: 128x128 tile, BK=64, 4 waves 2x2, single buffer, 4 blocks/CU.
// A source address per-lane pre-swizzled (Vb linear); B from baked-swizzled WvT.
#define BK 64
template<int PRE>
__global__ __launch_bounds__(256, PRE ? 4 : 3)
void k_big(const float* __restrict__ V, const u16* __restrict__ Vb,
           const u16* __restrict__ WvT, const float* __restrict__ bv,
           const float* __restrict__ hh, const float* __restrict__ Wz,
           float* __restrict__ zpart) {
  constexpr int LDA_ = PRE ? 64 : 72;
  __shared__ __align__(16) u16 As[128 * LDA_];
  __shared__ __align__(16) u16 Bs[128 * 64];
  __shared__ float wz_s[128], bv_s[128], hh_s[2][128];
  __shared__ float zred[4][64];

  int bid = blockIdx.x;
  int lin = (bid & 7) * 392 + (bid >> 3);   // 3136 = 8*392, bijective XCD swizzle
  int mt = lin >> 3, nt = lin & 7;          // 8 nt of one mt share an XCD
  int row0 = mt * 128, n0 = nt * 128;

  int tid = threadIdx.x;
  int lane = tid & 63, wid = tid >> 6;
  int wm = wid >> 1, wn = wid & 1;

  int b0 = row0 / Ss;
  int rsplit = (b0 + 1) * Ss - row0;        // rows >= rsplit -> batch b0+1
  int b1 = (rsplit < 128) ? b0 + 1 : b0;
  if (tid < 128) {
    wz_s[tid] = Wz[n0 + tid];
    bv_s[tid] = bv[n0 + tid];
    hh_s[0][tid] = hh[(size_t)b0 * Hh + n0 + tid];
    hh_s[1][tid] = hh[(size_t)b1 * Hh + n0 + tid];
  }

  f32x4 acc[4][4];
  f32x4 zz = {0.f, 0.f, 0.f, 0.f};
#pragma unroll
  for (int m = 0; m < 4; ++m)
#pragma unroll
    for (int n = 0; n < 4; ++n) acc[m][n] = zz;

  int srow = lane >> 3, scol = (lane & 7) * 8;   // staging lane offsets
  int ascol = scol ^ (srow << 3);                // A source col (inverse swizzle)
  int bxor = (lane & 7) << 3;                    // read-side XOR (row&7==lane&7)

  // PRE=0 reg staging state
  int arow = tid >> 3, acol8 = (tid & 7) * 8;
  const float* Ap = V + (size_t)(row0 + arow) * Hh + acol8;
  f32x4 av[8];
  if constexpr (!PRE) {
#pragma unroll
    for (int j = 0; j < 4; ++j) {
      av[2 * j]     = *(const f32x4*)(Ap + (size_t)j * 32 * Hh);
      av[2 * j + 1] = *(const f32x4*)(Ap + (size_t)j * 32 * Hh + 4);
    }
  }

  for (int kt = 0; kt < 16; ++kt) {
    int k0 = kt * BK;
    __syncthreads();                   // prev compute done; LDS writable
    if constexpr (PRE) {
#pragma unroll
      for (int i = 0; i < 4; ++i) {    // B staging
        int r = wid * 32 + i * 8;
        gload16(WvT + (size_t)(n0 + r + srow) * Hh + k0 + scol, &Bs[r * 64]);
      }
#pragma unroll
      for (int i = 0; i < 4; ++i) {    // A staging, pre-swizzled source
        int r = wid * 32 + i * 8;
        gload16(Vb + (size_t)(row0 + r + srow) * Hh + k0 + ascol, &As[r * 64]);
      }
    } else {
#pragma unroll
      for (int i = 0; i < 4; ++i) {
        int r = wid * 32 + i * 8;
        gload16(WvT + (size_t)(n0 + r + srow) * Hh + k0 + scol, &Bs[r * 64]);
      }
#pragma unroll
      for (int j = 0; j < 4; ++j) {
        u16x8 w;
        w[0] = f2b(av[2 * j].x);     w[1] = f2b(av[2 * j].y);
        w[2] = f2b(av[2 * j].z);     w[3] = f2b(av[2 * j].w);
        w[4] = f2b(av[2 * j + 1].x); w[5] = f2b(av[2 * j + 1].y);
        w[6] = f2b(av[2 * j + 1].z); w[7] = f2b(av[2 * j + 1].w);
        *(u16x8*)&As[(j * 32 + arow) * LDA_ + acol8] = w;
      }
      if (kt < 15) {
#pragma unroll
        for (int j = 0; j < 4; ++j) {
          av[2 * j]     = *(const f32x4*)(Ap + (size_t)j * 32 * Hh + k0 + BK);
          av[2 * j + 1] = *(const f32x4*)(Ap + (size_t)j * 32 * Hh + k0 + BK + 4);
        }
      }
    }
    __syncthreads();                   // drains staging
#pragma unroll
    for (int ks = 0; ks < 2; ++ks) {
      int kk = ks * 32 + (lane >> 4) * 8;
      s16x8 afr[4], bfr[4];
#pragma unroll
      for (int m = 0; m < 4; ++m) {
        int r = wm * 64 + m * 16 + (lane & 15);
        afr[m] = *(const s16x8*)&As[r * LDA_ + (PRE ? (kk ^ bxor) : kk)];
      }
#pragma unroll
      for (int n = 0; n < 4; ++n) {
        int r = wn * 64 + n * 16 + (lane & 15);
        bfr[n] = *(const s16x8*)&Bs[r * 64 + (kk ^ bxor)];
      }
#pragma unroll
      for (int m = 0; m < 4; ++m)
#pragma unroll
        for (int n = 0; n < 4; ++n)
          acc[m][n] = __builtin_amdgcn_mfma_f32_16x16x32_bf16(afr[m], bfr[n], acc[m][n], 0, 0, 0);
    }
  }

  // epilogue: z-partial over this block's 128 cols
  int cl = lane & 15, rg = lane >> 4;
  float pz[4][4];
#pragma unroll
  for (int m = 0; m < 4; ++m)
#pragma unroll
    for (int j = 0; j < 4; ++j) pz[m][j] = 0.f;
#pragma unroll
  for (int n = 0; n < 4; ++n) {
    int col = wn * 64 + n * 16 + cl;
    float wzv = wz_s[col], bvv = bv_s[col];
    float h0 = hh_s[0][col], h1 = hh_s[1][col];
#pragma unroll
    for (int m = 0; m < 4; ++m)
#pragma unroll
      for (int j = 0; j < 4; ++j) {
        int r = wm * 64 + m * 16 + rg * 4 + j;
        float hv = (r >= rsplit) ? h1 : h0;
        pz[m][j] += wzv * ftanh(acc[m][n][j] + bvv + hv);
      }
  }
#pragma unroll
  for (int m = 0; m < 4; ++m)
#pragma unroll
    for (int j = 0; j < 4; ++j) {
      float vv = pz[m][j];
      vv += __shfl_xor(vv, 1); vv += __shfl_xor(vv, 2);
      vv += __shfl_xor(vv, 4); vv += __shfl_xor(vv, 8);
      pz[m][j] = vv;
    }
  if (cl == 0) {
#pragma unroll
    for (int m = 0; m < 4; ++m)
#pragma unroll
      for (int j = 0; j < 4; ++j)
        zred[wid][m * 16 + rg * 4 + j] = pz[m][j];
  }
  __syncthreads();
  if (tid < 128) {
    int hhalf = tid >> 6, lr = tid & 63;
    zpart[(size_t)nt * Mm + row0 + tid] =
        zred[hhalf * 2][lr] + zred[hhalf * 2 + 1][lr];
  }
}

// ---------------- K4: softmax over 197 per batch (zS folded in) ----------------
__global__ __launch_bounds__(256) void k_softmax(const float* __restrict__ zpart,
                                                 const float* __restrict__ sv,
                                                 const float* __restrict__ hhp,
                                                 const float* __restrict__ Wz,
                                                 const float* __restrict__ bz,
                                                 float* __restrict__ outA) {
  int b = blockIdx.x, tid = threadIdx.x;
  int wid = tid >> 6, lane = tid & 63;
  __shared__ float redm[4], reds[4];
  __shared__ float zSsh;
  {
    int j0 = tid * 4;
    f32x4 s4 = *(const f32x4*)&sv[(size_t)b * Hh + j0];
    f32x4 h4 = *(const f32x4*)&hhp[(size_t)b * Hh + j0];
    f32x4 w4 = *(const f32x4*)&Wz[j0];
    float p = w4.x * ftanh(s4.x + h4.x) + w4.y * ftanh(s4.y + h4.y)
            + w4.z * ftanh(s4.z + h4.z) + w4.w * ftanh(s4.w + h4.w);
#pragma unroll
    for (int d = 1; d < 64; d <<= 1) p += __shfl_xor(p, d);
    if (lane == 0) redm[wid] = p;
    __syncthreads();
    if (tid == 0) zSsh = redm[0] + redm[1] + redm[2] + redm[3] + bz[0];
    __syncthreads();
  }
  float z = -1e30f;
  if (tid < Ss) {
    float s = 0.f;
#pragma unroll
    for (int nt = 0; nt < 8; ++nt) s += zpart[(size_t)nt * Mm + (size_t)b * Ss + tid];
    z = s + bz[0];
  } else if (tid == Ss) {
    z = zSsh;
  }
  float m = z;
#pragma unroll
  for (int d = 1; d < 64; d <<= 1) m = fmaxf(m, __shfl_xor(m, d));
  if (lane == 0) redm[wid] = m;
  __syncthreads();
  m = fmaxf(fmaxf(redm[0], redm[1]), fmaxf(redm[2], redm[3]));
  float e = (tid <= Ss) ? expf(z - m) : 0.f;
  float s = e;
#pragma unroll
  for (int d = 1; d < 64; d <<= 1) s += __shfl_xor(s, d);
  if (lane == 0) reds[wid] = s;
  __syncthreads();
  s = reds[0] + reds[1] + reds[2] + reds[3];
  if (tid <= Ss) outA[(size_t)b * SP1 + tid] = e / s;
}

// ---------------- K5: c[b,:] = sum_t a[b,t]*v[b,t,:] + a[b,S]*s[b,:] -----------
template<int PRE>
__global__ __launch_bounds__(256) void k_ctx(const float* __restrict__ V,
                                             const u16* __restrict__ Vb,
                                             const float* __restrict__ hs,
                                             const float* __restrict__ A,
                                             float* __restrict__ outC) {
  __shared__ float a_s[SP1];
  if constexpr (PRE) {
    int b = blockIdx.x;                 // 256 blocks, thread owns 4 cols
    int c4 = threadIdx.x * 4;
    if (threadIdx.x < SP1) a_s[threadIdx.x] = A[(size_t)b * SP1 + threadIdx.x];
    __syncthreads();
    f32x4 hv = *(const f32x4*)&hs[(size_t)b * 2048 + 1024 + c4];
    float aS = a_s[Ss];
    f32x4 acc = {aS * hv.x, aS * hv.y, aS * hv.z, aS * hv.w};
    const u16* vb = Vb + (size_t)b * Ss * Hh + c4;
#pragma unroll 4
    for (int t = 0; t < Ss; ++t) {
      u16x4 w = *(const u16x4*)(vb + (size_t)t * Hh);
      float at = a_s[t];
      acc.x += at * b2f(w[0]); acc.y += at * b2f(w[1]);
      acc.z += at * b2f(w[2]); acc.w += at * b2f(w[3]);
    }
    *(f32x4*)&outC[(size_t)b * Hh + c4] = acc;
  } else {
    int b = blockIdx.x >> 2;
    int col = (blockIdx.x & 3) * 256 + threadIdx.x;
    if (threadIdx.x < SP1) a_s[threadIdx.x] = A[(size_t)b * SP1 + threadIdx.x];
    __syncthreads();
    float acc = a_s[Ss] * hs[(size_t)b * 2048 + 1024 + col];
    const float* vb = V + (size_t)b * Ss * Hh + col;
#pragma unroll 4
    for (int t = 0; t < Ss; ++t) acc += a_s[t] * vb[(size_t)t * Hh];
    outC[(size_t)b * Hh + col] = acc;
  }
}

// -------------------------------------------------------------------------------
extern "C" void kernel_launch(void* const* d_in, const int* in_sizes, int n_in,
                              void* d_out, int out_size, void* d_ws, size_t ws_size,
                              hipStream_t stream) {
  const float* v   = (const float*)d_in[0];
  const float* h   = (const float*)d_in[1];
  const float* Wfc = (const float*)d_in[2];
  const float* bfc = (const float*)d_in[3];
  const float* Wv  = (const float*)d_in[4];
  const float* bv  = (const float*)d_in[5];
  const float* Wh  = (const float*)d_in[6];
  const float* bh  = (const float*)d_in[7];
  const float* Ws  = (const float*)d_in[8];
  const float* bs  = (const float*)d_in[9];
  const float* Wz  = (const float*)d_in[10];
  const float* bz  = (const float*)d_in[11];
  float* out  = (float*)d_out;
  float* outA = out;                         // [256][197]
  float* outC = out + (size_t)Bb * SP1;      // [256][1024]

  float* ws  = (float*)d_ws;
  float* hs  = ws;                  // 524288 f
  float* hh  = hs + 524288;         // 262144 f
  float* sv  = hh + 262144;         // 262144 f
  float* zp  = sv + 262144;         // 8*50176 f
  u16*  WvT  = (u16*)(zp + 401408); // 1M u16 (swizzled)
  u16*  Vb   = (u16*)((char*)(void*)WvT + 2097152);  // 50176*1024 u16 (LINEAR)

  // bytes needed through Vb: 7897088 + 102760448
  bool pre = ws_size >= 110657536ull;

  k_pre1<<<2816, 256, 0, stream>>>(v, Vb, (int)pre, Wv, WvT, h, Wfc, bfc, hs);
  k_dual<<<512, 256, 0, stream>>>(hs, Wh, bh, Ws, bs, hh, sv);
  if (pre) k_big<1><<<3136, 256, 0, stream>>>(v, Vb, WvT, bv, hh, Wz, zp);
  else     k_big<0><<<3136, 256, 0, stream>>>(v, Vb, WvT, bv, hh, Wz, zp);
  k_softmax<<<256, 256, 0, stream>>>(zp, sv, hh, Wz, bz, outA);
  if (pre) k_ctx<1><<<256, 256, 0, stream>>>(v, Vb, hs, outA, outC);
  else     k_ctx<0><<<1024, 256, 0, stream>>>(v, Vb, hs, outA, outC);
}